// Round 4
// baseline (2254.549 us; speedup 1.0000x reference)
//
#include <hip/hip_runtime.h>
#include <hip/hip_bf16.h>
#include <math.h>

#define BB 2
#define SS 2048
#define DD 1024
#define HH 16
#define MLPD 4096

typedef __attribute__((ext_vector_type(8))) short bf16x8;
typedef __attribute__((ext_vector_type(4))) float f32x4;
typedef __attribute__((ext_vector_type(4))) unsigned short us4;

#define AS1 __attribute__((address_space(1)))
#define AS3 __attribute__((address_space(3)))

static __device__ __forceinline__ void gl_lds16(const void* g, void* l) {
  __builtin_amdgcn_global_load_lds((const AS1 void*)g, (AS3 void*)l, 16, 0, 0);
}

static __device__ __forceinline__ float fast_exp2(float x) {
#if __has_builtin(__builtin_amdgcn_exp2f)
  return __builtin_amdgcn_exp2f(x);
#else
  return exp2f(x);
#endif
}
static __device__ __forceinline__ float fast_rcp(float x) {
#if __has_builtin(__builtin_amdgcn_rcpf)
  return __builtin_amdgcn_rcpf(x);
#else
  return 1.0f / x;
#endif
}

static __device__ __forceinline__ unsigned short f2bf(float f) {
  union { float f; unsigned int u; } v; v.f = f;
  unsigned int r = v.u + 0x7fffu + ((v.u >> 16) & 1u);
  return (unsigned short)(r >> 16);
}
static __device__ __forceinline__ float bf2f(unsigned short b) {
  return __uint_as_float(((unsigned int)b) << 16);
}

// tanh-form GELU via exp2 (max |err| vs erf-GELU ~3e-4; bf16 noise is 100x)
static __device__ __forceinline__ float gelu_f(float x) {
  float u = x * x;
  float z = x * fmaf(u, 0.0713548162f, 1.59576912f);  // 1.5957691*(x+0.044715x^3)
  float e = fast_exp2(z * -1.44269504f);
  return x * fast_rcp(1.0f + e);
}

// XOR swizzle: quad slot for (row, quad) pairs; spreads 64B-row DMA tiles
// so 16-lane c16 fragment reads hit banks 2-way (free) instead of 8-way.
static __device__ __forceinline__ int swz(int row) {
  return (row & 3) ^ ((row >> 2) & 3);
}

// ---------------------------------------------------------------------------
// fp32 [K][N] -> bf16 transposed [N][K], 32x32 LDS tiles
// ---------------------------------------------------------------------------
__global__ __launch_bounds__(256) void transpose_to_bf16(
    const float* __restrict__ src, unsigned short* __restrict__ dst,
    int K, int N) {
  __shared__ float tile[32][33];
  int t = threadIdx.x;
  int c = t & 31, rl = t >> 5;
  int bx = blockIdx.x, by = blockIdx.y;
#pragma unroll
  for (int i = 0; i < 4; ++i) {
    int row = rl * 4 + i;
    tile[row][c] = src[(size_t)(by * 32 + row) * N + bx * 32 + c];
  }
  __syncthreads();
#pragma unroll
  for (int i = 0; i < 4; ++i) {
    int n = rl * 4 + i;
    dst[(size_t)(bx * 32 + n) * K + by * 32 + c] = f2bf(tile[c][n]);
  }
}

// merged QKV weight transpose: grid.z picks wq/wk/wv
__global__ __launch_bounds__(256) void transpose_qkv(
    const float* __restrict__ wq, const float* __restrict__ wk,
    const float* __restrict__ wv, unsigned short* __restrict__ dst) {
  __shared__ float tile[32][33];
  const float* src = blockIdx.z == 0 ? wq : blockIdx.z == 1 ? wk : wv;
  unsigned short* d = dst + (size_t)blockIdx.z * 1024 * 1024;
  int t = threadIdx.x;
  int c = t & 31, rl = t >> 5;
  int bx = blockIdx.x, by = blockIdx.y;
#pragma unroll
  for (int i = 0; i < 4; ++i) {
    int row = rl * 4 + i;
    tile[row][c] = src[(size_t)(by * 32 + row) * DD + bx * 32 + c];
  }
  __syncthreads();
#pragma unroll
  for (int i = 0; i < 4; ++i) {
    int n = rl * 4 + i;
    d[(size_t)(bx * 32 + n) * DD + by * 32 + c] = f2bf(tile[c][n]);
  }
}

__global__ __launch_bounds__(256) void concat_bias(
    const float* __restrict__ bq, const float* __restrict__ bk,
    const float* __restrict__ bv, float* __restrict__ dst) {
  int i = blockIdx.x * 256 + threadIdx.x;
  if (i < 1024) dst[i] = bq[i];
  else if (i < 2048) dst[i] = bk[i - 1024];
  else if (i < 3072) dst[i] = bv[i - 2048];
}

// Combined mask, pre-scaled by log2(e), bf16
__global__ __launch_bounds__(256) void mask_prep(
    const float* __restrict__ dis, const float* __restrict__ cls,
    unsigned short* __restrict__ cm) {
  size_t i = ((size_t)blockIdx.x * 256 + threadIdx.x) * 4;
  float4 d = *(const float4*)(dis + i);
  float4 c = *(const float4*)(cls + i);
  us4 o;
  o[0] = f2bf((d.x + c.x) * 1.44269504f);
  o[1] = f2bf((d.y + c.y) * 1.44269504f);
  o[2] = f2bf((d.z + c.z) * 1.44269504f);
  o[3] = f2bf((d.w + c.w) * 1.44269504f);
  *(us4*)(cm + i) = o;
}

// ---------------------------------------------------------------------------
// LayerNorm -> bf16 out
// ---------------------------------------------------------------------------
template <bool BF_IN, bool ADD>
__global__ __launch_bounds__(256) void ln_bf16(
    const void* __restrict__ in, const float* __restrict__ add,
    const float* __restrict__ g, const float* __restrict__ beta,
    unsigned short* __restrict__ out) {
  int row = blockIdx.x;
  int t = threadIdx.x;
  float x[4];
  if (BF_IN) {
    us4 b4 = *(const us4*)((const unsigned short*)in + (size_t)row * DD + t * 4);
#pragma unroll
    for (int i = 0; i < 4; ++i) x[i] = bf2f(b4[i]);
  } else {
    float4 f4 = *(const float4*)((const float*)in + (size_t)row * DD + t * 4);
    x[0] = f4.x; x[1] = f4.y; x[2] = f4.z; x[3] = f4.w;
  }
  if (ADD) {
    float4 a4 = *(const float4*)(add + (size_t)row * DD + t * 4);
    x[0] += a4.x; x[1] += a4.y; x[2] += a4.z; x[3] += a4.w;
  }
  float s1 = x[0] + x[1] + x[2] + x[3];
  float s2 = x[0] * x[0] + x[1] * x[1] + x[2] * x[2] + x[3] * x[3];
#pragma unroll
  for (int off = 32; off > 0; off >>= 1) {
    s1 += __shfl_down(s1, off);
    s2 += __shfl_down(s2, off);
  }
  __shared__ float sa[4], sb[4];
  int wid = t >> 6;
  if ((t & 63) == 0) { sa[wid] = s1; sb[wid] = s2; }
  __syncthreads();
  s1 = sa[0] + sa[1] + sa[2] + sa[3];
  s2 = sb[0] + sb[1] + sb[2] + sb[3];
  float mean = s1 * (1.0f / 1024.0f);
  float var = s2 * (1.0f / 1024.0f) - mean * mean;
  float rstd = rsqrtf(var + 1e-5f);
  float4 gv = *(const float4*)(g + t * 4);
  float4 bv = *(const float4*)(beta + t * 4);
  us4 o;
  o[0] = f2bf((x[0] - mean) * rstd * gv.x + bv.x);
  o[1] = f2bf((x[1] - mean) * rstd * gv.y + bv.y);
  o[2] = f2bf((x[2] - mean) * rstd * gv.z + bv.z);
  o[3] = f2bf((x[3] - mean) * rstd * gv.w + bv.w);
  *(us4*)(out + (size_t)row * DD + t * 4) = o;
}

// ---------------------------------------------------------------------------
// bf16 MFMA GEMM, double-buffered DMA staging + XOR-swizzled LDS.
// 128xBN tile, BK=32, 256 thr. C = A[M,K] @ BT[N,K]^T + bias.
// ---------------------------------------------------------------------------
template <int BN, bool GELU, bool ADDSRC, bool OUT_BF16, bool SPLIT3>
__global__ __launch_bounds__(256) void gemm_bf16(
    const unsigned short* __restrict__ A, const unsigned short* __restrict__ BT,
    const float* __restrict__ bias, const unsigned short* __restrict__ addsrc,
    void* C0, void* C1, void* C2, int M, int N, int K) {
  constexpr int BJ = BN / 32;
  __shared__ __align__(16) unsigned short As[2][128][32];
  __shared__ __align__(16) unsigned short Bs[2][BN][32];
  int tid = threadIdx.x;
  int wave = tid >> 6, lane = tid & 63;
  int g = lane >> 4, c16 = lane & 15;
  int m0 = blockIdx.y * 128, n0 = blockIdx.x * BN;
  int wm = (wave >> 1) * 64, wn = (wave & 1) * (BN / 2);
  int lrow = lane >> 2;
  int lsw = (((lane & 3) ^ swz(lrow)) * 8);   // swizzled source quad (bf16 units)
  int vA = ((g ^ swz(c16)) * 8);              // swizzled read slot
  const int KI = K / 32;

  // prologue stage kt=0 -> buf 0
  {
#pragma unroll
    for (int c = 0; c < 2; ++c) {
      int chunk = wave * 2 + c;
      gl_lds16(A + (size_t)(m0 + chunk * 16 + lrow) * K + lsw, &As[0][chunk * 16][0]);
    }
#pragma unroll
    for (int c = 0; c < BN / 64; ++c) {
      int chunk = wave * (BN / 64) + c;
      gl_lds16(BT + (size_t)(n0 + chunk * 16 + lrow) * K + lsw, &Bs[0][chunk * 16][0]);
    }
  }
  f32x4 acc[4][BJ] = {};
  for (int kt = 0; kt < KI; ++kt) {
    __syncthreads();  // drains vmcnt -> tile kt ready; prev reads done
    if (kt + 1 < KI) {
      int k0 = (kt + 1) * 32;
      int bn = (kt + 1) & 1;
#pragma unroll
      for (int c = 0; c < 2; ++c) {
        int chunk = wave * 2 + c;
        gl_lds16(A + (size_t)(m0 + chunk * 16 + lrow) * K + k0 + lsw, &As[bn][chunk * 16][0]);
      }
#pragma unroll
      for (int c = 0; c < BN / 64; ++c) {
        int chunk = wave * (BN / 64) + c;
        gl_lds16(BT + (size_t)(n0 + chunk * 16 + lrow) * K + k0 + lsw, &Bs[bn][chunk * 16][0]);
      }
    }
    int buf = kt & 1;
    bf16x8 a[4], b[BJ];
#pragma unroll
    for (int i = 0; i < 4; ++i) a[i] = *(const bf16x8*)&As[buf][wm + i * 16 + c16][vA];
#pragma unroll
    for (int j = 0; j < BJ; ++j) b[j] = *(const bf16x8*)&Bs[buf][wn + j * 16 + c16][vA];
#pragma unroll
    for (int i = 0; i < 4; ++i)
#pragma unroll
      for (int j = 0; j < BJ; ++j)
        acc[i][j] = __builtin_amdgcn_mfma_f32_16x16x32_bf16(a[i], b[j], acc[i][j], 0, 0, 0);
  }
  // epilogue
  unsigned short* dstb = nullptr;
  int lc0 = 0;
  if (SPLIT3) {  // 128-wide tiles never straddle 1024 groups
    int which = n0 >> 10;
    dstb = (unsigned short*)(which == 0 ? C0 : which == 1 ? C1 : C2);
    lc0 = n0 & 1023;
  }
#pragma unroll
  for (int j = 0; j < BJ; ++j) {
    int coff = wn + j * 16 + c16;
    float bj = bias[n0 + coff];
#pragma unroll
    for (int i = 0; i < 4; ++i) {
#pragma unroll
      for (int r = 0; r < 4; ++r) {
        int row = m0 + wm + i * 16 + g * 4 + r;
        float cval = acc[i][j][r] + bj;
        if (GELU) cval = gelu_f(cval);
        if (ADDSRC) cval += bf2f(addsrc[(size_t)row * N + n0 + coff]);
        if (SPLIT3) {
          dstb[(size_t)row * 1024 + lc0 + coff] = f2bf(cval);
        } else if (OUT_BF16) {
          ((unsigned short*)C0)[(size_t)row * N + n0 + coff] = f2bf(cval);
        } else {
          ((float*)C0)[(size_t)row * N + n0 + coff] = cval;
        }
      }
    }
  }
}

// ---------------------------------------------------------------------------
// MFMA flash attention, double-buffered. Block = 128 q-rows, 256 thr, 4 waves;
// each wave owns 32 q-rows (2 strips of 16). No-max softmax; denominator via
// all-ones MFMA. K staged by swizzled DMA; V register-transposed; masks
// register-prefetched one k-tile ahead.
// ---------------------------------------------------------------------------
__global__ __launch_bounds__(256) void attn_mfma(
    const unsigned short* __restrict__ q, const unsigned short* __restrict__ k,
    const unsigned short* __restrict__ v, const unsigned short* __restrict__ cm,
    unsigned short* __restrict__ outO) {
  __shared__ __align__(16) unsigned short Ks[2][2][64][32];  // [buf][half][key][32]
  __shared__ __align__(16) unsigned short Vt[2][64][72];     // [buf][hd][key]
  __shared__ __align__(16) unsigned short Ps[128][72];
  int tid = threadIdx.x;
  int wave = tid >> 6, lane = tid & 63;
  int g = lane >> 4, c16 = lane & 15;
  int qt = blockIdx.x, h = blockIdx.y, b = blockIdx.z;
  int s0 = qt * 128;
  size_t headoff = (size_t)b * SS * DD + (size_t)h * SS * 64;
  const unsigned short* qb = q + headoff;
  const unsigned short* kb = k + headoff;
  const unsigned short* vb = v + headoff;
  const unsigned short* cmb = cm + (size_t)b * SS * SS;

  int lrow = lane >> 2;
  int lsw = (((lane & 3) ^ swz(lrow)) * 8);
  int vK = ((g ^ swz(c16)) * 8);

  // Q fragments: 2 strips x 2 k-halves
  bf16x8 qf[2][2];
#pragma unroll
  for (int s2 = 0; s2 < 2; ++s2) {
    size_t qrow = (size_t)(s0 + wave * 32 + s2 * 16 + c16) * 64;
    qf[s2][0] = *(const bf16x8*)(qb + qrow + g * 8);
    qf[s2][1] = *(const bf16x8*)(qb + qrow + 32 + g * 8);
  }
  bf16x8 ones;
#pragma unroll
  for (int j = 0; j < 8; ++j) ones[j] = (short)0x3F80;
  f32x4 o[2][4] = {};
  f32x4 ol[2] = {};
  unsigned short cmr[2][2][4][4];
  bf16x8 vv[2];
  const float scale2 = 0.18033688f;  // 0.125*log2(e)

  // ---- prologue: tile 0 ----
  {
    int kidx = wave * 2;  // two K chunks per wave
#pragma unroll
    for (int c = 0; c < 2; ++c) {
      int idx = kidx + c, half = idx >> 2, r0 = (idx & 3) * 16;
      gl_lds16(kb + (size_t)(r0 + lrow) * 64 + half * 32 + lsw, &Ks[0][half][r0][0]);
    }
#pragma unroll
    for (int i = 0; i < 2; ++i)
      vv[i] = *(const bf16x8*)(vb + (size_t)lane * 64 + (wave + i * 4) * 8);
#pragma unroll
    for (int s2 = 0; s2 < 2; ++s2)
#pragma unroll
      for (int t = 0; t < 4; ++t)
#pragma unroll
        for (int r = 0; r < 4; ++r) {
          int row = s0 + wave * 32 + s2 * 16 + g * 4 + r;
          cmr[0][s2][t][r] = cmb[(size_t)row * SS + t * 16 + c16];
        }
#pragma unroll
    for (int i = 0; i < 2; ++i)
#pragma unroll
      for (int j = 0; j < 8; ++j)
        Vt[0][(wave + i * 4) * 8 + j][lane] = (unsigned short)vv[i][j];
  }

  for (int kt = 0; kt < 32; ++kt) {
    __syncthreads();  // tile kt staged (vmcnt drain) + V/P writes visible
    int buf = kt & 1;
    int ktn = (kt + 1 < 32) ? kt + 1 : 31;
    int bufn = (kt + 1) & 1;
    // prefetch tile kt+1
    {
      int kidx = wave * 2;
#pragma unroll
      for (int c = 0; c < 2; ++c) {
        int idx = kidx + c, half = idx >> 2, r0 = (idx & 3) * 16;
        gl_lds16(kb + (size_t)(ktn * 64 + r0 + lrow) * 64 + half * 32 + lsw,
                 &Ks[bufn][half][r0][0]);
      }
#pragma unroll
      for (int i = 0; i < 2; ++i)
        vv[i] = *(const bf16x8*)(vb + (size_t)(ktn * 64 + lane) * 64 + (wave + i * 4) * 8);
#pragma unroll
      for (int s2 = 0; s2 < 2; ++s2)
#pragma unroll
        for (int t = 0; t < 4; ++t)
#pragma unroll
          for (int r = 0; r < 4; ++r) {
            int row = s0 + wave * 32 + s2 * 16 + g * 4 + r;
            cmr[bufn][s2][t][r] = cmb[(size_t)row * SS + ktn * 64 + t * 16 + c16];
          }
    }
    // S = Q @ K^T : 2 strips x 4 col-tiles
    f32x4 s[2][4] = {};
#pragma unroll
    for (int t = 0; t < 4; ++t) {
      bf16x8 b0 = *(const bf16x8*)&Ks[buf][0][t * 16 + c16][vK];
      bf16x8 b1 = *(const bf16x8*)&Ks[buf][1][t * 16 + c16][vK];
#pragma unroll
      for (int s2 = 0; s2 < 2; ++s2) {
        s[s2][t] = __builtin_amdgcn_mfma_f32_16x16x32_bf16(qf[s2][0], b0, s[s2][t], 0, 0, 0);
        s[s2][t] = __builtin_amdgcn_mfma_f32_16x16x32_bf16(qf[s2][1], b1, s[s2][t], 0, 0, 0);
      }
    }
    // P = exp2(qk*scale2 + cm) -> Ps (wave-private rows; in-order LDS)
#pragma unroll
    for (int s2 = 0; s2 < 2; ++s2)
#pragma unroll
      for (int t = 0; t < 4; ++t)
#pragma unroll
        for (int r = 0; r < 4; ++r) {
          float p = fast_exp2(fmaf(s[s2][t][r], scale2, bf2f(cmr[buf][s2][t][r])));
          Ps[wave * 32 + s2 * 16 + g * 4 + r][t * 16 + c16] =
              (unsigned short)(__float_as_uint(p) >> 16);
        }
    // scatter V(kt+1) into Vt[bufn] (readers use Vt[buf] this iter)
#pragma unroll
    for (int i = 0; i < 2; ++i)
#pragma unroll
      for (int j = 0; j < 8; ++j)
        Vt[bufn][(wave + i * 4) * 8 + j][lane] = (unsigned short)vv[i][j];
    // O += P @ V ; l += P @ 1
#pragma unroll
    for (int ks = 0; ks < 2; ++ks) {
#pragma unroll
      for (int s2 = 0; s2 < 2; ++s2) {
        bf16x8 pa = *(const bf16x8*)&Ps[wave * 32 + s2 * 16 + c16][ks * 32 + g * 8];
#pragma unroll
        for (int t2 = 0; t2 < 4; ++t2) {
          bf16x8 vb8 = *(const bf16x8*)&Vt[buf][t2 * 16 + c16][ks * 32 + g * 8];
          o[s2][t2] = __builtin_amdgcn_mfma_f32_16x16x32_bf16(pa, vb8, o[s2][t2], 0, 0, 0);
        }
        ol[s2] = __builtin_amdgcn_mfma_f32_16x16x32_bf16(pa, ones, ol[s2], 0, 0, 0);
      }
    }
  }
  // epilogue
#pragma unroll
  for (int s2 = 0; s2 < 2; ++s2) {
    float inv[4];
#pragma unroll
    for (int r = 0; r < 4; ++r) inv[r] = fast_rcp(ol[s2][r]);
#pragma unroll
    for (int t2 = 0; t2 < 4; ++t2)
#pragma unroll
      for (int r = 0; r < 4; ++r) {
        int srow = s0 + wave * 32 + s2 * 16 + g * 4 + r;
        outO[headoff + (size_t)srow * 64 + t2 * 16 + c16] = f2bf(o[s2][t2][r] * inv[r]);
      }
  }
}

// ---------------------------------------------------------------------------
extern "C" void kernel_launch(void* const* d_in, const int* in_sizes, int n_in,
                              void* d_out, int out_size, void* d_ws, size_t ws_size,
                              hipStream_t stream) {
  const float* x    = (const float*)d_in[0];
  const float* dis  = (const float*)d_in[1];
  const float* cls  = (const float*)d_in[2];
  const float* wq   = (const float*)d_in[3];
  const float* bq   = (const float*)d_in[4];
  const float* wk   = (const float*)d_in[5];
  const float* bk   = (const float*)d_in[6];
  const float* wv   = (const float*)d_in[7];
  const float* bv   = (const float*)d_in[8];
  const float* ln1g = (const float*)d_in[9];
  const float* ln1b = (const float*)d_in[10];
  const float* ln2g = (const float*)d_in[11];
  const float* ln2b = (const float*)d_in[12];
  const float* w1   = (const float*)d_in[13];
  const float* b1   = (const float*)d_in[14];
  const float* w2   = (const float*)d_in[15];
  const float* b2   = (const float*)d_in[16];
  float* out = (float*)d_out;
  char* ws = (char*)d_ws;

  // Workspace (bytes), peak 81.9 MB
  unsigned short* qkvwT = (unsigned short*)(ws + 0);           // 6 MB
  unsigned short* w1T   = (unsigned short*)(ws + 6291456);     // 8 MB
  unsigned short* w2T   = (unsigned short*)(ws + 14680064);    // 8 MB
  float*          qkvb  = (float*)(ws + 23068672);             // 12 KB
  unsigned short* r1    = (unsigned short*)(ws + 23134208);    // 8 MB: h1 -> attnO
  unsigned short* qbuf  = (unsigned short*)(ws + 31522816);    // 8 MB
  unsigned short* kbuf  = (unsigned short*)(ws + 39911424);    // 8 MB
  unsigned short* vbuf  = (unsigned short*)(ws + 48300032);    // 8 MB
  unsigned short* h2    = (unsigned short*)(ws + 56688640);    // 8 MB
  unsigned short* cmb   = (unsigned short*)(ws + 65077248);    // 16.78 MB
  unsigned short* mm    = (unsigned short*)(ws + 23134208);    // 32 MB overlays r1/q/k/v
  unsigned short* h1 = r1;
  unsigned short* attnO = r1;

  const int rows = BB * SS;  // 4096

  // Prep
  transpose_qkv<<<dim3(DD / 32, DD / 32, 3), 256, 0, stream>>>(wq, wk, wv, qkvwT);
  transpose_to_bf16<<<dim3(MLPD / 32, DD / 32), 256, 0, stream>>>(w1, w1T, DD, MLPD);
  transpose_to_bf16<<<dim3(DD / 32, MLPD / 32), 256, 0, stream>>>(w2, w2T, MLPD, DD);
  concat_bias<<<12, 256, 0, stream>>>(bq, bk, bv, qkvb);
  mask_prep<<<8192, 256, 0, stream>>>(dis, cls, cmb);

  // LN1 -> h1 (bf16)
  ln_bf16<false, false><<<rows, 256, 0, stream>>>(x, nullptr, ln1g, ln1b, h1);

  // Fused QKV GEMM: M=4096, N=3072, K=1024
  gemm_bf16<128, false, false, true, true><<<dim3(3072 / 128, rows / 128), 256, 0, stream>>>(
      h1, qkvwT, qkvb, nullptr, qbuf, kbuf, vbuf, rows, 3072, DD);

  // Attention: 128 q-rows per block, 256 thr
  attn_mfma<<<dim3(SS / 128, HH, BB), 256, 0, stream>>>(qbuf, kbuf, vbuf, cmb, attnO);

  // LN2(attn + x) -> h2 (bf16)
  ln_bf16<true, true><<<rows, 256, 0, stream>>>(attnO, x, ln2g, ln2b, h2);

  // MLP1 + GELU: M=4096, N=4096, K=1024 -> mm (bf16)
  gemm_bf16<128, true, false, true, false><<<dim3(MLPD / 128, rows / 128), 256, 0, stream>>>(
      h2, w1T, b1, nullptr, mm, nullptr, nullptr, rows, MLPD, DD);

  // MLP2 + residual(h2): M=4096, N=1024, K=4096 -> out (fp32)
  gemm_bf16<64, false, true, false, false><<<dim3(DD / 64, rows / 128), 256, 0, stream>>>(
      mm, w2T, b2, h2, out, nullptr, nullptr, rows, DD, MLPD);
}

// Round 5
// 429.699 us; speedup vs baseline: 5.2468x; 5.2468x over previous
//
#include <hip/hip_runtime.h>
#include <hip/hip_bf16.h>
#include <math.h>

#define BB 2
#define SS 2048
#define DD 1024
#define HH 16
#define MLPD 4096

typedef __attribute__((ext_vector_type(8))) short bf16x8;
typedef __attribute__((ext_vector_type(4))) float f32x4;
typedef __attribute__((ext_vector_type(4))) unsigned short us4;

#define AS1 __attribute__((address_space(1)))
#define AS3 __attribute__((address_space(3)))

static __device__ __forceinline__ void gl_lds16(const void* g, void* l) {
  __builtin_amdgcn_global_load_lds((const AS1 void*)g, (AS3 void*)l, 16, 0, 0);
}

static __device__ __forceinline__ float fast_exp2(float x) {
#if __has_builtin(__builtin_amdgcn_exp2f)
  return __builtin_amdgcn_exp2f(x);
#else
  return exp2f(x);
#endif
}
static __device__ __forceinline__ float fast_rcp(float x) {
#if __has_builtin(__builtin_amdgcn_rcpf)
  return __builtin_amdgcn_rcpf(x);
#else
  return 1.0f / x;
#endif
}

static __device__ __forceinline__ unsigned short f2bf(float f) {
  union { float f; unsigned int u; } v; v.f = f;
  unsigned int r = v.u + 0x7fffu + ((v.u >> 16) & 1u);
  return (unsigned short)(r >> 16);
}
static __device__ __forceinline__ float bf2f(unsigned short b) {
  return __uint_as_float(((unsigned int)b) << 16);
}

// tanh-form GELU via exp2 (max |err| vs erf-GELU ~3e-4; bf16 noise is 100x)
static __device__ __forceinline__ float gelu_f(float x) {
  float u = x * x;
  float z = x * fmaf(u, 0.0713548162f, 1.59576912f);
  float e = fast_exp2(z * -1.44269504f);
  return x * fast_rcp(1.0f + e);
}

// XOR swizzle: spreads 64B-row DMA/staged tiles so 16-row fragment reads hit
// banks 2-way (free) instead of 8-way. swz(row) depends only on row&15.
static __device__ __forceinline__ int swz(int row) {
  return (row & 3) ^ ((row >> 2) & 3);
}

// ---------------------------------------------------------------------------
// fp32 [K][N] -> bf16 transposed [N][K], 32x32 LDS tiles
// ---------------------------------------------------------------------------
__global__ __launch_bounds__(256) void transpose_to_bf16(
    const float* __restrict__ src, unsigned short* __restrict__ dst,
    int K, int N) {
  __shared__ float tile[32][33];
  int t = threadIdx.x;
  int c = t & 31, rl = t >> 5;
  int bx = blockIdx.x, by = blockIdx.y;
#pragma unroll
  for (int i = 0; i < 4; ++i) {
    int row = rl * 4 + i;
    tile[row][c] = src[(size_t)(by * 32 + row) * N + bx * 32 + c];
  }
  __syncthreads();
#pragma unroll
  for (int i = 0; i < 4; ++i) {
    int n = rl * 4 + i;
    dst[(size_t)(bx * 32 + n) * K + by * 32 + c] = f2bf(tile[c][n]);
  }
}

// merged QKV weight transpose: grid.z picks wq/wk/wv
__global__ __launch_bounds__(256) void transpose_qkv(
    const float* __restrict__ wq, const float* __restrict__ wk,
    const float* __restrict__ wv, unsigned short* __restrict__ dst) {
  __shared__ float tile[32][33];
  const float* src = blockIdx.z == 0 ? wq : blockIdx.z == 1 ? wk : wv;
  unsigned short* d = dst + (size_t)blockIdx.z * 1024 * 1024;
  int t = threadIdx.x;
  int c = t & 31, rl = t >> 5;
  int bx = blockIdx.x, by = blockIdx.y;
#pragma unroll
  for (int i = 0; i < 4; ++i) {
    int row = rl * 4 + i;
    tile[row][c] = src[(size_t)(by * 32 + row) * DD + bx * 32 + c];
  }
  __syncthreads();
#pragma unroll
  for (int i = 0; i < 4; ++i) {
    int n = rl * 4 + i;
    d[(size_t)(bx * 32 + n) * DD + by * 32 + c] = f2bf(tile[c][n]);
  }
}

__global__ __launch_bounds__(256) void concat_bias(
    const float* __restrict__ bq, const float* __restrict__ bk,
    const float* __restrict__ bv, float* __restrict__ dst) {
  int i = blockIdx.x * 256 + threadIdx.x;
  if (i < 1024) dst[i] = bq[i];
  else if (i < 2048) dst[i] = bk[i - 1024];
  else if (i < 3072) dst[i] = bv[i - 2048];
}

// Combined mask, pre-scaled by log2(e), bf16
__global__ __launch_bounds__(256) void mask_prep(
    const float* __restrict__ dis, const float* __restrict__ cls,
    unsigned short* __restrict__ cm) {
  size_t i = ((size_t)blockIdx.x * 256 + threadIdx.x) * 4;
  float4 d = *(const float4*)(dis + i);
  float4 c = *(const float4*)(cls + i);
  us4 o;
  o[0] = f2bf((d.x + c.x) * 1.44269504f);
  o[1] = f2bf((d.y + c.y) * 1.44269504f);
  o[2] = f2bf((d.z + c.z) * 1.44269504f);
  o[3] = f2bf((d.w + c.w) * 1.44269504f);
  *(us4*)(cm + i) = o;
}

// ---------------------------------------------------------------------------
// LayerNorm -> bf16 out
// ---------------------------------------------------------------------------
template <bool BF_IN, bool ADD>
__global__ __launch_bounds__(256) void ln_bf16(
    const void* __restrict__ in, const float* __restrict__ add,
    const float* __restrict__ g, const float* __restrict__ beta,
    unsigned short* __restrict__ out) {
  int row = blockIdx.x;
  int t = threadIdx.x;
  float x[4];
  if (BF_IN) {
    us4 b4 = *(const us4*)((const unsigned short*)in + (size_t)row * DD + t * 4);
#pragma unroll
    for (int i = 0; i < 4; ++i) x[i] = bf2f(b4[i]);
  } else {
    float4 f4 = *(const float4*)((const float*)in + (size_t)row * DD + t * 4);
    x[0] = f4.x; x[1] = f4.y; x[2] = f4.z; x[3] = f4.w;
  }
  if (ADD) {
    float4 a4 = *(const float4*)(add + (size_t)row * DD + t * 4);
    x[0] += a4.x; x[1] += a4.y; x[2] += a4.z; x[3] += a4.w;
  }
  float s1 = x[0] + x[1] + x[2] + x[3];
  float s2 = x[0] * x[0] + x[1] * x[1] + x[2] * x[2] + x[3] * x[3];
#pragma unroll
  for (int off = 32; off > 0; off >>= 1) {
    s1 += __shfl_down(s1, off);
    s2 += __shfl_down(s2, off);
  }
  __shared__ float sa[4], sb[4];
  int wid = t >> 6;
  if ((t & 63) == 0) { sa[wid] = s1; sb[wid] = s2; }
  __syncthreads();
  s1 = sa[0] + sa[1] + sa[2] + sa[3];
  s2 = sb[0] + sb[1] + sb[2] + sb[3];
  float mean = s1 * (1.0f / 1024.0f);
  float var = s2 * (1.0f / 1024.0f) - mean * mean;
  float rstd = rsqrtf(var + 1e-5f);
  float4 gv = *(const float4*)(g + t * 4);
  float4 bv = *(const float4*)(beta + t * 4);
  us4 o;
  o[0] = f2bf((x[0] - mean) * rstd * gv.x + bv.x);
  o[1] = f2bf((x[1] - mean) * rstd * gv.y + bv.y);
  o[2] = f2bf((x[2] - mean) * rstd * gv.z + bv.z);
  o[3] = f2bf((x[3] - mean) * rstd * gv.w + bv.w);
  *(us4*)(out + (size_t)row * DD + t * 4) = o;
}

// ---------------------------------------------------------------------------
// bf16 MFMA GEMM, double-buffered DMA staging + XOR-swizzled LDS.
// 128xBN tile, BK=32, 256 thr. C = A[M,K] @ BT[N,K]^T + bias.
// (unchanged from round 4 — measured ~80 us faster than round 3 GEMMs)
// ---------------------------------------------------------------------------
template <int BN, bool GELU, bool ADDSRC, bool OUT_BF16, bool SPLIT3>
__global__ __launch_bounds__(256) void gemm_bf16(
    const unsigned short* __restrict__ A, const unsigned short* __restrict__ BT,
    const float* __restrict__ bias, const unsigned short* __restrict__ addsrc,
    void* C0, void* C1, void* C2, int M, int N, int K) {
  constexpr int BJ = BN / 32;
  __shared__ __align__(16) unsigned short As[2][128][32];
  __shared__ __align__(16) unsigned short Bs[2][BN][32];
  int tid = threadIdx.x;
  int wave = tid >> 6, lane = tid & 63;
  int g = lane >> 4, c16 = lane & 15;
  int m0 = blockIdx.y * 128, n0 = blockIdx.x * BN;
  int wm = (wave >> 1) * 64, wn = (wave & 1) * (BN / 2);
  int lrow = lane >> 2;
  int lsw = (((lane & 3) ^ swz(lrow)) * 8);
  int vA = ((g ^ swz(c16)) * 8);
  const int KI = K / 32;

  {
#pragma unroll
    for (int c = 0; c < 2; ++c) {
      int chunk = wave * 2 + c;
      gl_lds16(A + (size_t)(m0 + chunk * 16 + lrow) * K + lsw, &As[0][chunk * 16][0]);
    }
#pragma unroll
    for (int c = 0; c < BN / 64; ++c) {
      int chunk = wave * (BN / 64) + c;
      gl_lds16(BT + (size_t)(n0 + chunk * 16 + lrow) * K + lsw, &Bs[0][chunk * 16][0]);
    }
  }
  f32x4 acc[4][BJ] = {};
  for (int kt = 0; kt < KI; ++kt) {
    __syncthreads();
    if (kt + 1 < KI) {
      int k0 = (kt + 1) * 32;
      int bn = (kt + 1) & 1;
#pragma unroll
      for (int c = 0; c < 2; ++c) {
        int chunk = wave * 2 + c;
        gl_lds16(A + (size_t)(m0 + chunk * 16 + lrow) * K + k0 + lsw, &As[bn][chunk * 16][0]);
      }
#pragma unroll
      for (int c = 0; c < BN / 64; ++c) {
        int chunk = wave * (BN / 64) + c;
        gl_lds16(BT + (size_t)(n0 + chunk * 16 + lrow) * K + k0 + lsw, &Bs[bn][chunk * 16][0]);
      }
    }
    int buf = kt & 1;
    bf16x8 a[4], b[BJ];
#pragma unroll
    for (int i = 0; i < 4; ++i) a[i] = *(const bf16x8*)&As[buf][wm + i * 16 + c16][vA];
#pragma unroll
    for (int j = 0; j < BJ; ++j) b[j] = *(const bf16x8*)&Bs[buf][wn + j * 16 + c16][vA];
#pragma unroll
    for (int i = 0; i < 4; ++i)
#pragma unroll
      for (int j = 0; j < BJ; ++j)
        acc[i][j] = __builtin_amdgcn_mfma_f32_16x16x32_bf16(a[i], b[j], acc[i][j], 0, 0, 0);
  }
  unsigned short* dstb = nullptr;
  int lc0 = 0;
  if (SPLIT3) {
    int which = n0 >> 10;
    dstb = (unsigned short*)(which == 0 ? C0 : which == 1 ? C1 : C2);
    lc0 = n0 & 1023;
  }
#pragma unroll
  for (int j = 0; j < BJ; ++j) {
    int coff = wn + j * 16 + c16;
    float bj = bias[n0 + coff];
#pragma unroll
    for (int i = 0; i < 4; ++i) {
#pragma unroll
      for (int r = 0; r < 4; ++r) {
        int row = m0 + wm + i * 16 + g * 4 + r;
        float cval = acc[i][j][r] + bj;
        if (GELU) cval = gelu_f(cval);
        if (ADDSRC) cval += bf2f(addsrc[(size_t)row * N + n0 + coff]);
        if (SPLIT3) {
          dstb[(size_t)row * 1024 + lc0 + coff] = f2bf(cval);
        } else if (OUT_BF16) {
          ((unsigned short*)C0)[(size_t)row * N + n0 + coff] = f2bf(cval);
        } else {
          ((float*)C0)[(size_t)row * N + n0 + coff] = cval;
        }
      }
    }
  }
}

// ---------------------------------------------------------------------------
// MFMA flash attention, register-prefetch pipeline (all prefetch state in
// STATICALLY-indexed registers — no dynamic reg-array indexing!).
// Block = 128 q-rows, 512 thr (8 waves), each wave owns 16 q-rows.
// No-max softmax (|s| provably < ~4); denominator via all-ones MFMA B-frag.
// K tile staged through regs into XOR-swizzled LDS; V transposed via scatter.
// Pipeline: barrier / commit regs->LDS / barrier / prefetch kt+1 + compute kt.
// No vmem is in flight at any barrier -> no vmcnt-drain stall.
// ---------------------------------------------------------------------------
__global__ __launch_bounds__(512) void attn_mfma(
    const unsigned short* __restrict__ q, const unsigned short* __restrict__ k,
    const unsigned short* __restrict__ v, const unsigned short* __restrict__ cm,
    unsigned short* __restrict__ outO) {
  __shared__ __align__(16) unsigned short Ks[2][64][32];  // [half][key][32] swizzled
  __shared__ __align__(16) unsigned short Vt[64][72];     // [hd][key]
  __shared__ __align__(16) unsigned short Ps[128][72];
  int tid = threadIdx.x;
  int wave = tid >> 6, lane = tid & 63;
  int g = lane >> 4, c16 = lane & 15;
  int qt = blockIdx.x, h = blockIdx.y, b = blockIdx.z;
  int s0 = qt * 128;
  int wr = wave * 16;  // this wave's q-row strip
  size_t headoff = (size_t)b * SS * DD + (size_t)h * SS * 64;
  const unsigned short* qb = q + headoff;
  const unsigned short* kb = k + headoff;
  const unsigned short* vb = v + headoff;
  const unsigned short* cmb = cm + (size_t)b * SS * SS;

  // K staging map: thread t -> (key = t>>3, seg = t&7); 16B per thread,
  // fully coalesced 1KB per wave. LDS slot: half=seg>>2, quad=(seg&3)^swz(key).
  int kkey = tid >> 3, kseg = tid & 7;
  unsigned short* kdst = &Ks[kseg >> 2][kkey][((kseg & 3) ^ swz(kkey)) * 8];
  const unsigned short* ksrc = kb + (size_t)kkey * 64 + kseg * 8;
  // V staging: thread t -> (key = lane, seg = wave)
  const unsigned short* vsrc = vb + (size_t)lane * 64 + wave * 8;
  int vK = (g ^ swz(c16)) * 8;  // swizzled fragment read slot

  // Q fragments (2 k-halves)
  bf16x8 qf0, qf1;
  {
    size_t qrow = (size_t)(s0 + wr + c16) * 64;
    qf0 = *(const bf16x8*)(qb + qrow);
    qf0 = *(const bf16x8*)(qb + qrow + g * 8);
    qf1 = *(const bf16x8*)(qb + qrow + 32 + g * 8);
  }
  bf16x8 ones;
#pragma unroll
  for (int j = 0; j < 8; ++j) ones[j] = (short)0x3F80;
  f32x4 o[4] = {};
  f32x4 ol = {};
  const float scale2 = 0.18033688f;  // 0.125*log2(e)

  // prologue: tile 0 into regs
  bf16x8 kreg = *(const bf16x8*)(ksrc);
  bf16x8 vreg = *(const bf16x8*)(vsrc);
  unsigned short cmc[4][4];
#pragma unroll
  for (int t = 0; t < 4; ++t)
#pragma unroll
    for (int r = 0; r < 4; ++r)
      cmc[t][r] = cmb[(size_t)(s0 + wr + g * 4 + r) * SS + t * 16 + c16];

  for (int kt = 0; kt < 32; ++kt) {
    __syncthreads();  // readers of tile kt-1 done; LDS writable
    *(bf16x8*)kdst = kreg;
#pragma unroll
    for (int j = 0; j < 8; ++j) Vt[wave * 8 + j][lane] = (unsigned short)vreg[j];
    __syncthreads();  // tile kt visible (no vmem outstanding here)

    // prefetch tile kt+1 into regs (kt=31 redundantly reloads 31; in-bounds)
    int ktn = kt + 1 < 32 ? kt + 1 : 31;
    bf16x8 kregN = *(const bf16x8*)(ksrc + (size_t)ktn * 4096);
    bf16x8 vregN = *(const bf16x8*)(vsrc + (size_t)ktn * 4096);
    unsigned short cmN[4][4];
#pragma unroll
    for (int t = 0; t < 4; ++t)
#pragma unroll
      for (int r = 0; r < 4; ++r)
        cmN[t][r] = cmb[(size_t)(s0 + wr + g * 4 + r) * SS + ktn * 64 + t * 16 + c16];

    // S = Q @ K^T (4 col-tiles x 2 k-halves)
    f32x4 s[4] = {};
#pragma unroll
    for (int t = 0; t < 4; ++t) {
      bf16x8 b0 = *(const bf16x8*)&Ks[0][t * 16 + c16][vK];
      bf16x8 b1 = *(const bf16x8*)&Ks[1][t * 16 + c16][vK];
      s[t] = __builtin_amdgcn_mfma_f32_16x16x32_bf16(qf0, b0, s[t], 0, 0, 0);
      s[t] = __builtin_amdgcn_mfma_f32_16x16x32_bf16(qf1, b1, s[t], 0, 0, 0);
    }
    // P = exp2(qk*scale2 + cm) -> Ps strip (wave-private rows)
#pragma unroll
    for (int t = 0; t < 4; ++t)
#pragma unroll
      for (int r = 0; r < 4; ++r) {
        float p = fast_exp2(fmaf(s[t][r], scale2, bf2f(cmc[t][r])));
        Ps[wr + g * 4 + r][t * 16 + c16] = (unsigned short)(__float_as_uint(p) >> 16);
      }
    // O += P @ V ; l += P @ 1
#pragma unroll
    for (int ks = 0; ks < 2; ++ks) {
      bf16x8 pa = *(const bf16x8*)&Ps[wr + c16][ks * 32 + g * 8];
#pragma unroll
      for (int t2 = 0; t2 < 4; ++t2) {
        bf16x8 vb8 = *(const bf16x8*)&Vt[t2 * 16 + c16][ks * 32 + g * 8];
        o[t2] = __builtin_amdgcn_mfma_f32_16x16x32_bf16(pa, vb8, o[t2], 0, 0, 0);
      }
      ol = __builtin_amdgcn_mfma_f32_16x16x32_bf16(pa, ones, ol, 0, 0, 0);
    }
    // commit prefetch (static register moves)
    kreg = kregN;
    vreg = vregN;
#pragma unroll
    for (int t = 0; t < 4; ++t)
#pragma unroll
      for (int r = 0; r < 4; ++r) cmc[t][r] = cmN[t][r];
  }
  // epilogue: O / l
  float inv[4];
#pragma unroll
  for (int r = 0; r < 4; ++r) inv[r] = fast_rcp(ol[r]);
#pragma unroll
  for (int t2 = 0; t2 < 4; ++t2)
#pragma unroll
    for (int r = 0; r < 4; ++r) {
      int srow = s0 + wr + g * 4 + r;
      outO[headoff + (size_t)srow * 64 + t2 * 16 + c16] = f2bf(o[t2][r] * inv[r]);
    }
}

// ---------------------------------------------------------------------------
extern "C" void kernel_launch(void* const* d_in, const int* in_sizes, int n_in,
                              void* d_out, int out_size, void* d_ws, size_t ws_size,
                              hipStream_t stream) {
  const float* x    = (const float*)d_in[0];
  const float* dis  = (const float*)d_in[1];
  const float* cls  = (const float*)d_in[2];
  const float* wq   = (const float*)d_in[3];
  const float* bq   = (const float*)d_in[4];
  const float* wk   = (const float*)d_in[5];
  const float* bk   = (const float*)d_in[6];
  const float* wv   = (const float*)d_in[7];
  const float* bv   = (const float*)d_in[8];
  const float* ln1g = (const float*)d_in[9];
  const float* ln1b = (const float*)d_in[10];
  const float* ln2g = (const float*)d_in[11];
  const float* ln2b = (const float*)d_in[12];
  const float* w1   = (const float*)d_in[13];
  const float* b1   = (const float*)d_in[14];
  const float* w2   = (const float*)d_in[15];
  const float* b2   = (const float*)d_in[16];
  float* out = (float*)d_out;
  char* ws = (char*)d_ws;

  unsigned short* qkvwT = (unsigned short*)(ws + 0);           // 6 MB
  unsigned short* w1T   = (unsigned short*)(ws + 6291456);     // 8 MB
  unsigned short* w2T   = (unsigned short*)(ws + 14680064);    // 8 MB
  float*          qkvb  = (float*)(ws + 23068672);             // 12 KB
  unsigned short* r1    = (unsigned short*)(ws + 23134208);    // 8 MB: h1 -> attnO
  unsigned short* qbuf  = (unsigned short*)(ws + 31522816);    // 8 MB
  unsigned short* kbuf  = (unsigned short*)(ws + 39911424);    // 8 MB
  unsigned short* vbuf  = (unsigned short*)(ws + 48300032);    // 8 MB
  unsigned short* h2    = (unsigned short*)(ws + 56688640);    // 8 MB
  unsigned short* cmb   = (unsigned short*)(ws + 65077248);    // 16.78 MB
  unsigned short* mm    = (unsigned short*)(ws + 23134208);    // 32 MB overlays r1/q/k/v
  unsigned short* h1 = r1;
  unsigned short* attnO = r1;

  const int rows = BB * SS;  // 4096

  transpose_qkv<<<dim3(DD / 32, DD / 32, 3), 256, 0, stream>>>(wq, wk, wv, qkvwT);
  transpose_to_bf16<<<dim3(MLPD / 32, DD / 32), 256, 0, stream>>>(w1, w1T, DD, MLPD);
  transpose_to_bf16<<<dim3(DD / 32, MLPD / 32), 256, 0, stream>>>(w2, w2T, MLPD, DD);
  concat_bias<<<12, 256, 0, stream>>>(bq, bk, bv, qkvb);
  mask_prep<<<8192, 256, 0, stream>>>(dis, cls, cmb);

  ln_bf16<false, false><<<rows, 256, 0, stream>>>(x, nullptr, ln1g, ln1b, h1);

  gemm_bf16<128, false, false, true, true><<<dim3(3072 / 128, rows / 128), 256, 0, stream>>>(
      h1, qkvwT, qkvb, nullptr, qbuf, kbuf, vbuf, rows, 3072, DD);

  attn_mfma<<<dim3(SS / 128, HH, BB), 512, 0, stream>>>(qbuf, kbuf, vbuf, cmb, attnO);

  ln_bf16<true, true><<<rows, 256, 0, stream>>>(attnO, x, ln2g, ln2b, h2);

  gemm_bf16<128, true, false, true, false><<<dim3(MLPD / 128, rows / 128), 256, 0, stream>>>(
      h2, w1T, b1, nullptr, mm, nullptr, nullptr, rows, MLPD, DD);

  gemm_bf16<64, false, true, false, false><<<dim3(DD / 64, rows / 128), 256, 0, stream>>>(
      mm, w2T, b2, h2, out, nullptr, nullptr, rows, DD, MLPD);
}

// Round 7
// 413.958 us; speedup vs baseline: 5.4463x; 1.0380x over previous
//
#include <hip/hip_runtime.h>
#include <hip/hip_bf16.h>
#include <math.h>

#define BB 2
#define SS 2048
#define DD 1024
#define HH 16
#define MLPD 4096

typedef __attribute__((ext_vector_type(8))) short bf16x8;
typedef __attribute__((ext_vector_type(4))) float f32x4;
typedef __attribute__((ext_vector_type(4))) unsigned short us4;

static __device__ __forceinline__ float fast_exp2(float x) {
#if __has_builtin(__builtin_amdgcn_exp2f)
  return __builtin_amdgcn_exp2f(x);
#else
  return exp2f(x);
#endif
}
static __device__ __forceinline__ float fast_rcp(float x) {
#if __has_builtin(__builtin_amdgcn_rcpf)
  return __builtin_amdgcn_rcpf(x);
#else
  return 1.0f / x;
#endif
}

static __device__ __forceinline__ unsigned short f2bf(float f) {
  union { float f; unsigned int u; } v; v.f = f;
  unsigned int r = v.u + 0x7fffu + ((v.u >> 16) & 1u);
  return (unsigned short)(r >> 16);
}
static __device__ __forceinline__ float bf2f(unsigned short b) {
  return __uint_as_float(((unsigned int)b) << 16);
}

// tanh-form GELU via exp2 (max |err| vs erf-GELU ~3e-4; bf16 noise is 100x)
static __device__ __forceinline__ float gelu_f(float x) {
  float u = x * x;
  float z = x * fmaf(u, 0.0713548162f, 1.59576912f);
  float e = fast_exp2(z * -1.44269504f);
  return x * fast_rcp(1.0f + e);
}

// XOR swizzle: spreads 64B-row tiles so 16-row fragment reads hit banks
// 2-way (free) instead of 8-way. Depends only on row&15.
static __device__ __forceinline__ int swz(int row) {
  return (row & 3) ^ ((row >> 2) & 3);
}

// ---------------------------------------------------------------------------
// fp32 [K][N] -> bf16 transposed [N][K], 32x32 LDS tiles
// ---------------------------------------------------------------------------
__global__ __launch_bounds__(256) void transpose_to_bf16(
    const float* __restrict__ src, unsigned short* __restrict__ dst,
    int K, int N) {
  __shared__ float tile[32][33];
  int t = threadIdx.x;
  int c = t & 31, rl = t >> 5;
  int bx = blockIdx.x, by = blockIdx.y;
#pragma unroll
  for (int i = 0; i < 4; ++i) {
    int row = rl * 4 + i;
    tile[row][c] = src[(size_t)(by * 32 + row) * N + bx * 32 + c];
  }
  __syncthreads();
#pragma unroll
  for (int i = 0; i < 4; ++i) {
    int n = rl * 4 + i;
    dst[(size_t)(bx * 32 + n) * K + by * 32 + c] = f2bf(tile[c][n]);
  }
}

// merged QKV weight transpose: grid.z picks wq/wk/wv
__global__ __launch_bounds__(256) void transpose_qkv(
    const float* __restrict__ wq, const float* __restrict__ wk,
    const float* __restrict__ wv, unsigned short* __restrict__ dst) {
  __shared__ float tile[32][33];
  const float* src = blockIdx.z == 0 ? wq : blockIdx.z == 1 ? wk : wv;
  unsigned short* d = dst + (size_t)blockIdx.z * 1024 * 1024;
  int t = threadIdx.x;
  int c = t & 31, rl = t >> 5;
  int bx = blockIdx.x, by = blockIdx.y;
#pragma unroll
  for (int i = 0; i < 4; ++i) {
    int row = rl * 4 + i;
    tile[row][c] = src[(size_t)(by * 32 + row) * DD + bx * 32 + c];
  }
  __syncthreads();
#pragma unroll
  for (int i = 0; i < 4; ++i) {
    int n = rl * 4 + i;
    d[(size_t)(bx * 32 + n) * DD + by * 32 + c] = f2bf(tile[c][n]);
  }
}

__global__ __launch_bounds__(256) void concat_bias(
    const float* __restrict__ bq, const float* __restrict__ bk,
    const float* __restrict__ bv, float* __restrict__ dst) {
  int i = blockIdx.x * 256 + threadIdx.x;
  if (i < 1024) dst[i] = bq[i];
  else if (i < 2048) dst[i] = bk[i - 1024];
  else if (i < 3072) dst[i] = bv[i - 2048];
}

// Combined mask, pre-scaled by log2(e), bf16
__global__ __launch_bounds__(256) void mask_prep(
    const float* __restrict__ dis, const float* __restrict__ cls,
    unsigned short* __restrict__ cm) {
  size_t i = ((size_t)blockIdx.x * 256 + threadIdx.x) * 4;
  float4 d = *(const float4*)(dis + i);
  float4 c = *(const float4*)(cls + i);
  us4 o;
  o[0] = f2bf((d.x + c.x) * 1.44269504f);
  o[1] = f2bf((d.y + c.y) * 1.44269504f);
  o[2] = f2bf((d.z + c.z) * 1.44269504f);
  o[3] = f2bf((d.w + c.w) * 1.44269504f);
  *(us4*)(cm + i) = o;
}

// ---------------------------------------------------------------------------
// LayerNorm -> bf16 out
// ---------------------------------------------------------------------------
template <bool BF_IN, bool ADD>
__global__ __launch_bounds__(256) void ln_bf16(
    const void* __restrict__ in, const float* __restrict__ add,
    const float* __restrict__ g, const float* __restrict__ beta,
    unsigned short* __restrict__ out) {
  int row = blockIdx.x;
  int t = threadIdx.x;
  float x[4];
  if (BF_IN) {
    us4 b4 = *(const us4*)((const unsigned short*)in + (size_t)row * DD + t * 4);
#pragma unroll
    for (int i = 0; i < 4; ++i) x[i] = bf2f(b4[i]);
  } else {
    float4 f4 = *(const float4*)((const float*)in + (size_t)row * DD + t * 4);
    x[0] = f4.x; x[1] = f4.y; x[2] = f4.z; x[3] = f4.w;
  }
  if (ADD) {
    float4 a4 = *(const float4*)(add + (size_t)row * DD + t * 4);
    x[0] += a4.x; x[1] += a4.y; x[2] += a4.z; x[3] += a4.w;
  }
  float s1 = x[0] + x[1] + x[2] + x[3];
  float s2 = x[0] * x[0] + x[1] * x[1] + x[2] * x[2] + x[3] * x[3];
#pragma unroll
  for (int off = 32; off > 0; off >>= 1) {
    s1 += __shfl_down(s1, off);
    s2 += __shfl_down(s2, off);
  }
  __shared__ float sa[4], sb[4];
  int wid = t >> 6;
  if ((t & 63) == 0) { sa[wid] = s1; sb[wid] = s2; }
  __syncthreads();
  s1 = sa[0] + sa[1] + sa[2] + sa[3];
  s2 = sb[0] + sb[1] + sb[2] + sb[3];
  float mean = s1 * (1.0f / 1024.0f);
  float var = s2 * (1.0f / 1024.0f) - mean * mean;
  float rstd = rsqrtf(var + 1e-5f);
  float4 gv = *(const float4*)(g + t * 4);
  float4 bv = *(const float4*)(beta + t * 4);
  us4 o;
  o[0] = f2bf((x[0] - mean) * rstd * gv.x + bv.x);
  o[1] = f2bf((x[1] - mean) * rstd * gv.y + bv.y);
  o[2] = f2bf((x[2] - mean) * rstd * gv.z + bv.z);
  o[3] = f2bf((x[3] - mean) * rstd * gv.w + bv.w);
  *(us4*)(out + (size_t)row * DD + t * 4) = o;
}

// ---------------------------------------------------------------------------
// bf16 MFMA GEMM with 2-deep REGISTER prefetch pipeline (attn-style):
// two statically-named reg sets, loop unrolled x2, SINGLE LDS buffer,
// 2 barriers/iter. A tile's global loads are issued 2 iterations before its
// LDS commit -> ~2 compute phases of latency slack, and no vmem is in
// flight at any barrier (no vmcnt-drain stall).
// 128xBN tile, BK=32, 256 thr. C = A[M,K] @ BT[N,K]^T + bias.
// ---------------------------------------------------------------------------
template <int BN, bool GELU, bool ADDSRC, bool OUT_BF16, bool SPLIT3>
__global__ __launch_bounds__(256) void gemm_bf16(
    const unsigned short* __restrict__ A, const unsigned short* __restrict__ BT,
    const float* __restrict__ bias, const unsigned short* __restrict__ addsrc,
    void* C0, void* C1, void* C2, int M, int N, int K) {
  constexpr int BJ = BN / 32;    // B-frag tiles per wave (4 or 2)
  constexpr int BCH = BN / 64;   // B staging chunks per wave (2 or 1)
  __shared__ __align__(16) unsigned short As[128][32];
  __shared__ __align__(16) unsigned short Bs[BN][32];
  int tid = threadIdx.x;
  int wave = tid >> 6, lane = tid & 63;
  int g = lane >> 4, c16 = lane & 15;
  int m0 = blockIdx.y * 128, n0 = blockIdx.x * BN;
  int wm = (wave >> 1) * 64, wn = (wave & 1) * (BN / 2);
  int lrow = lane >> 2, lq = lane & 3;
  int dq = (lq ^ swz(lrow)) * 8;     // swizzled LDS dest quad
  // staging maps: wave stages A rows [wave*32, wave*32+32); B rows per BCH
  const unsigned short* aS = A + (size_t)(m0 + wave * 32 + lrow) * K + lq * 8;
  unsigned short* aD0 = &As[wave * 32 + lrow][dq];
  unsigned short* aD1 = &As[wave * 32 + 16 + lrow][dq];
  const unsigned short* bS = BT + (size_t)(n0 + wave * (BCH * 16) + lrow) * K + lq * 8;
  unsigned short* bD0 = &Bs[wave * (BCH * 16) + lrow][dq];
  unsigned short* bD1 = &Bs[(wave * (BCH * 16) + 16 + lrow) % BN][dq];  // BCH==2 only (fix: +lrow)
  int vA = (g ^ swz(c16)) * 8;       // swizzled fragment read slot
  const int KI = K / 32;             // 32 or 128 (even)
  const size_t rK = 16 * (size_t)K;

  // prologue: tile 0 -> set a, tile 1 -> set b
  bf16x8 a0a = *(const bf16x8*)(aS);
  bf16x8 a1a = *(const bf16x8*)(aS + rK);
  bf16x8 b0a = *(const bf16x8*)(bS);
  bf16x8 b1a;
  if constexpr (BCH == 2) b1a = *(const bf16x8*)(bS + rK);
  bf16x8 a0b = *(const bf16x8*)(aS + 32);
  bf16x8 a1b = *(const bf16x8*)(aS + rK + 32);
  bf16x8 b0b = *(const bf16x8*)(bS + 32);
  bf16x8 b1b;
  if constexpr (BCH == 2) b1b = *(const bf16x8*)(bS + rK + 32);

  f32x4 acc[4][BJ] = {};
  for (int kt = 0; kt < KI; kt += 2) {
    // ---- half 1: tile kt (set a) ----
    __syncthreads();                 // previous compute's LDS reads done
    *(bf16x8*)aD0 = a0a;
    *(bf16x8*)aD1 = a1a;
    *(bf16x8*)bD0 = b0a;
    if constexpr (BCH == 2) *(bf16x8*)bD1 = b1a;
    __syncthreads();                 // tile kt visible
    if (kt + 2 < KI) {
      int ko = (kt + 2) * 32;
      a0a = *(const bf16x8*)(aS + ko);
      a1a = *(const bf16x8*)(aS + rK + ko);
      b0a = *(const bf16x8*)(bS + ko);
      if constexpr (BCH == 2) b1a = *(const bf16x8*)(bS + rK + ko);
    }
    {
      bf16x8 a[4], b[BJ];
#pragma unroll
      for (int i = 0; i < 4; ++i) a[i] = *(const bf16x8*)&As[wm + i * 16 + c16][vA];
#pragma unroll
      for (int j = 0; j < BJ; ++j) b[j] = *(const bf16x8*)&Bs[wn + j * 16 + c16][vA];
#pragma unroll
      for (int i = 0; i < 4; ++i)
#pragma unroll
        for (int j = 0; j < BJ; ++j)
          acc[i][j] = __builtin_amdgcn_mfma_f32_16x16x32_bf16(a[i], b[j], acc[i][j], 0, 0, 0);
    }
    // ---- half 2: tile kt+1 (set b) ----
    __syncthreads();
    *(bf16x8*)aD0 = a0b;
    *(bf16x8*)aD1 = a1b;
    *(bf16x8*)bD0 = b0b;
    if constexpr (BCH == 2) *(bf16x8*)bD1 = b1b;
    __syncthreads();
    if (kt + 3 < KI) {
      int ko = (kt + 3) * 32;
      a0b = *(const bf16x8*)(aS + ko);
      a1b = *(const bf16x8*)(aS + rK + ko);
      b0b = *(const bf16x8*)(bS + ko);
      if constexpr (BCH == 2) b1b = *(const bf16x8*)(bS + rK + ko);
    }
    {
      bf16x8 a[4], b[BJ];
#pragma unroll
      for (int i = 0; i < 4; ++i) a[i] = *(const bf16x8*)&As[wm + i * 16 + c16][vA];
#pragma unroll
      for (int j = 0; j < BJ; ++j) b[j] = *(const bf16x8*)&Bs[wn + j * 16 + c16][vA];
#pragma unroll
      for (int i = 0; i < 4; ++i)
#pragma unroll
        for (int j = 0; j < BJ; ++j)
          acc[i][j] = __builtin_amdgcn_mfma_f32_16x16x32_bf16(a[i], b[j], acc[i][j], 0, 0, 0);
    }
  }
  // epilogue
  unsigned short* dstb = nullptr;
  int lc0 = 0;
  if (SPLIT3) {
    int which = n0 >> 10;
    dstb = (unsigned short*)(which == 0 ? C0 : which == 1 ? C1 : C2);
    lc0 = n0 & 1023;
  }
#pragma unroll
  for (int j = 0; j < BJ; ++j) {
    int coff = wn + j * 16 + c16;
    float bj = bias[n0 + coff];
#pragma unroll
    for (int i = 0; i < 4; ++i) {
#pragma unroll
      for (int r = 0; r < 4; ++r) {
        int row = m0 + wm + i * 16 + g * 4 + r;
        float cval = acc[i][j][r] + bj;
        if (GELU) cval = gelu_f(cval);
        if (ADDSRC) cval += bf2f(addsrc[(size_t)row * N + n0 + coff]);
        if (SPLIT3) {
          dstb[(size_t)row * 1024 + lc0 + coff] = f2bf(cval);
        } else if (OUT_BF16) {
          ((unsigned short*)C0)[(size_t)row * N + n0 + coff] = f2bf(cval);
        } else {
          ((float*)C0)[(size_t)row * N + n0 + coff] = cval;
        }
      }
    }
  }
}

// ---------------------------------------------------------------------------
// MFMA flash attention, register-prefetch pipeline (round-5, proven).
// Block = 128 q-rows, 512 thr (8 waves), each wave owns 16 q-rows.
// No-max softmax; denominator via all-ones MFMA B-frag.
// ---------------------------------------------------------------------------
__global__ __launch_bounds__(512) void attn_mfma(
    const unsigned short* __restrict__ q, const unsigned short* __restrict__ k,
    const unsigned short* __restrict__ v, const unsigned short* __restrict__ cm,
    unsigned short* __restrict__ outO) {
  __shared__ __align__(16) unsigned short Ks[2][64][32];  // [half][key][32] swizzled
  __shared__ __align__(16) unsigned short Vt[64][72];     // [hd][key]
  __shared__ __align__(16) unsigned short Ps[128][72];
  int tid = threadIdx.x;
  int wave = tid >> 6, lane = tid & 63;
  int g = lane >> 4, c16 = lane & 15;
  int qt = blockIdx.x, h = blockIdx.y, b = blockIdx.z;
  int s0 = qt * 128;
  int wr = wave * 16;
  size_t headoff = (size_t)b * SS * DD + (size_t)h * SS * 64;
  const unsigned short* qb = q + headoff;
  const unsigned short* kb = k + headoff;
  const unsigned short* vb = v + headoff;
  const unsigned short* cmb = cm + (size_t)b * SS * SS;

  int kkey = tid >> 3, kseg = tid & 7;
  unsigned short* kdst = &Ks[kseg >> 2][kkey][((kseg & 3) ^ swz(kkey)) * 8];
  const unsigned short* ksrc = kb + (size_t)kkey * 64 + kseg * 8;
  const unsigned short* vsrc = vb + (size_t)lane * 64 + wave * 8;
  int vK = (g ^ swz(c16)) * 8;

  bf16x8 qf0, qf1;
  {
    size_t qrow = (size_t)(s0 + wr + c16) * 64;
    qf0 = *(const bf16x8*)(qb + qrow + g * 8);
    qf1 = *(const bf16x8*)(qb + qrow + 32 + g * 8);
  }
  bf16x8 ones;
#pragma unroll
  for (int j = 0; j < 8; ++j) ones[j] = (short)0x3F80;
  f32x4 o[4] = {};
  f32x4 ol = {};
  const float scale2 = 0.18033688f;  // 0.125*log2(e)

  bf16x8 kreg = *(const bf16x8*)(ksrc);
  bf16x8 vreg = *(const bf16x8*)(vsrc);
  unsigned short cmc[4][4];
#pragma unroll
  for (int t = 0; t < 4; ++t)
#pragma unroll
    for (int r = 0; r < 4; ++r)
      cmc[t][r] = cmb[(size_t)(s0 + wr + g * 4 + r) * SS + t * 16 + c16];

  for (int kt = 0; kt < 32; ++kt) {
    __syncthreads();
    *(bf16x8*)kdst = kreg;
#pragma unroll
    for (int j = 0; j < 8; ++j) Vt[wave * 8 + j][lane] = (unsigned short)vreg[j];
    __syncthreads();

    int ktn = kt + 1 < 32 ? kt + 1 : 31;
    bf16x8 kregN = *(const bf16x8*)(ksrc + (size_t)ktn * 4096);
    bf16x8 vregN = *(const bf16x8*)(vsrc + (size_t)ktn * 4096);
    unsigned short cmN[4][4];
#pragma unroll
    for (int t = 0; t < 4; ++t)
#pragma unroll
      for (int r = 0; r < 4; ++r)
        cmN[t][r] = cmb[(size_t)(s0 + wr + g * 4 + r) * SS + ktn * 64 + t * 16 + c16];

    f32x4 s[4] = {};
#pragma unroll
    for (int t = 0; t < 4; ++t) {
      bf16x8 b0 = *(const bf16x8*)&Ks[0][t * 16 + c16][vK];
      bf16x8 b1 = *(const bf16x8*)&Ks[1][t * 16 + c16][vK];
      s[t] = __builtin_amdgcn_mfma_f32_16x16x32_bf16(qf0, b0, s[t], 0, 0, 0);
      s[t] = __builtin_amdgcn_mfma_f32_16x16x32_bf16(qf1, b1, s[t], 0, 0, 0);
    }
#pragma unroll
    for (int t = 0; t < 4; ++t)
#pragma unroll
      for (int r = 0; r < 4; ++r) {
        float p = fast_exp2(fmaf(s[t][r], scale2, bf2f(cmc[t][r])));
        Ps[wr + g * 4 + r][t * 16 + c16] = (unsigned short)(__float_as_uint(p) >> 16);
      }
#pragma unroll
    for (int ks = 0; ks < 2; ++ks) {
      bf16x8 pa = *(const bf16x8*)&Ps[wr + c16][ks * 32 + g * 8];
#pragma unroll
      for (int t2 = 0; t2 < 4; ++t2) {
        bf16x8 vb8 = *(const bf16x8*)&Vt[t2 * 16 + c16][ks * 32 + g * 8];
        o[t2] = __builtin_amdgcn_mfma_f32_16x16x32_bf16(pa, vb8, o[t2], 0, 0, 0);
      }
      ol = __builtin_amdgcn_mfma_f32_16x16x32_bf16(pa, ones, ol, 0, 0, 0);
    }
    kreg = kregN;
    vreg = vregN;
#pragma unroll
    for (int t = 0; t < 4; ++t)
#pragma unroll
      for (int r = 0; r < 4; ++r) cmc[t][r] = cmN[t][r];
  }
  float inv[4];
#pragma unroll
  for (int r = 0; r < 4; ++r) inv[r] = fast_rcp(ol[r]);
#pragma unroll
  for (int t2 = 0; t2 < 4; ++t2)
#pragma unroll
    for (int r = 0; r < 4; ++r) {
      int srow = s0 + wr + g * 4 + r;
      outO[headoff + (size_t)srow * 64 + t2 * 16 + c16] = f2bf(o[t2][r] * inv[r]);
    }
}

// ---------------------------------------------------------------------------
extern "C" void kernel_launch(void* const* d_in, const int* in_sizes, int n_in,
                              void* d_out, int out_size, void* d_ws, size_t ws_size,
                              hipStream_t stream) {
  const float* x    = (const float*)d_in[0];
  const float* dis  = (const float*)d_in[1];
  const float* cls  = (const float*)d_in[2];
  const float* wq   = (const float*)d_in[3];
  const float* bq   = (const float*)d_in[4];
  const float* wk   = (const float*)d_in[5];
  const float* bk   = (const float*)d_in[6];
  const float* wv   = (const float*)d_in[7];
  const float* bv   = (const float*)d_in[8];
  const float* ln1g = (const float*)d_in[9];
  const float* ln1b = (const float*)d_in[10];
  const float* ln2g = (const float*)d_in[11];
  const float* ln2b = (const float*)d_in[12];
  const float* w1   = (const float*)d_in[13];
  const float* b1   = (const float*)d_in[14];
  const float* w2   = (const float*)d_in[15];
  const float* b2   = (const float*)d_in[16];
  float* out = (float*)d_out;
  char* ws = (char*)d_ws;

  unsigned short* qkvwT = (unsigned short*)(ws + 0);           // 6 MB
  unsigned short* w1T   = (unsigned short*)(ws + 6291456);     // 8 MB
  unsigned short* w2T   = (unsigned short*)(ws + 14680064);    // 8 MB
  float*          qkvb  = (float*)(ws + 23068672);             // 12 KB
  unsigned short* r1    = (unsigned short*)(ws + 23134208);    // 8 MB: h1 -> attnO
  unsigned short* qbuf  = (unsigned short*)(ws + 31522816);    // 8 MB
  unsigned short* kbuf  = (unsigned short*)(ws + 39911424);    // 8 MB
  unsigned short* vbuf  = (unsigned short*)(ws + 48300032);    // 8 MB
  unsigned short* h2    = (unsigned short*)(ws + 56688640);    // 8 MB
  unsigned short* cmb   = (unsigned short*)(ws + 65077248);    // 16.78 MB
  unsigned short* mm    = (unsigned short*)(ws + 23134208);    // 32 MB overlays r1/q/k/v
  unsigned short* h1 = r1;
  unsigned short* attnO = r1;

  const int rows = BB * SS;  // 4096

  transpose_qkv<<<dim3(DD / 32, DD / 32, 3), 256, 0, stream>>>(wq, wk, wv, qkvwT);
  transpose_to_bf16<<<dim3(MLPD / 32, DD / 32), 256, 0, stream>>>(w1, w1T, DD, MLPD);
  transpose_to_bf16<<<dim3(DD / 32, MLPD / 32), 256, 0, stream>>>(w2, w2T, MLPD, DD);
  concat_bias<<<12, 256, 0, stream>>>(bq, bk, bv, qkvb);
  mask_prep<<<8192, 256, 0, stream>>>(dis, cls, cmb);

  ln_bf16<false, false><<<rows, 256, 0, stream>>>(x, nullptr, ln1g, ln1b, h1);

  gemm_bf16<128, false, false, true, true><<<dim3(3072 / 128, rows / 128), 256, 0, stream>>>(
      h1, qkvwT, qkvb, nullptr, qbuf, kbuf, vbuf, rows, 3072, DD);

  attn_mfma<<<dim3(SS / 128, HH, BB), 512, 0, stream>>>(qbuf, kbuf, vbuf, cmb, attnO);

  ln_bf16<true, true><<<rows, 256, 0, stream>>>(attnO, x, ln2g, ln2b, h2);

  gemm_bf16<128, true, false, true, false><<<dim3(MLPD / 128, rows / 128), 256, 0, stream>>>(
      h2, w1T, b1, nullptr, mm, nullptr, nullptr, rows, MLPD, DD);

  gemm_bf16<64, false, true, false, false><<<dim3(DD / 64, rows / 128), 256, 0, stream>>>(
      mm, w2T, b2, h2, out, nullptr, nullptr, rows, DD, MLPD);
}